// Round 1
// 1582.222 us; speedup vs baseline: 1.1936x; 1.1936x over previous
//
#include <hip/hip_runtime.h>
#include <math.h>

#define TZ 8
#define TH 96
#define TW 192
#define C 192
#define NHEADS 6
#define HDIM 32
#define LW 144
#define NWIN 1024
#define NTOK 147456
#define NPOS 3312
#define QSCALE 0.17677669529663687f

typedef unsigned short u16;
typedef __attribute__((ext_vector_type(8))) short bf8_t;
typedef __attribute__((ext_vector_type(4))) float f4_t;

__device__ __forceinline__ float bf2f(u16 u) {
    union { unsigned int i; float f; } c; c.i = ((unsigned int)u) << 16; return c.f;
}
__device__ __forceinline__ u16 f2bf(float f) {
    union { float f; unsigned int i; } c; c.f = f;
    unsigned int x = c.i;
    x += 0x7fffu + ((x >> 16) & 1u);   // RNE
    return (u16)(x >> 16);
}

// windowed row -> token (with optional roll). Row r in [0, NTOK).
__device__ __forceinline__ int win_row_to_token(int r, int roll) {
    int wi = r / LW, l = r % LW;
    int nz = wi >> 8, nh = (wi >> 4) & 15, nw = wi & 15;
    int iz = l / 72, rr = l % 72, ih = rr / 12, iw = rr % 12;
    int z = nz * 2 + iz, h = nh * 6 + ih, w = nw * 12 + iw;
    if (roll) {
        z = (z + 1) & 7;
        h += 3; if (h >= TH) h -= TH;
        w += 6; if (w >= TW) w -= TW;
    }
    return (z * TH + h) * TW + w;
}

// ---------------- fused LN (+gather/roll) -> bf16, one wave per row ----------------
__global__ __launch_bounds__(256) void ln_kernel(
    const float* __restrict__ x, const float* __restrict__ g,
    const float* __restrict__ b, u16* __restrict__ xnc,
    int row0, int windowed, int roll)
{
    int wave = threadIdx.x >> 6;
    int lane = threadIdx.x & 63;
    int dl = blockIdx.x * 4 + wave;          // row (full-size pass: global row)
    int d = row0 + dl;
    int src = windowed ? win_row_to_token(d, roll) : d;
    const float* xr = x + (size_t)src * C;
    float v0 = xr[lane], v1 = xr[lane + 64], v2 = xr[lane + 128];
    float s = v0 + v1 + v2;
    float sq = v0 * v0 + v1 * v1 + v2 * v2;
    #pragma unroll
    for (int off = 32; off > 0; off >>= 1) {
        s  += __shfl_xor(s, off, 64);
        sq += __shfl_xor(sq, off, 64);
    }
    float mean = s * (1.0f / 192.0f);
    float var  = sq * (1.0f / 192.0f) - mean * mean;
    float rstd = rsqrtf(var + 1e-5f);
    u16* orow = xnc + (size_t)dl * C;
    orow[lane]       = f2bf((v0 - mean) * rstd * g[lane]       + b[lane]);
    orow[lane + 64]  = f2bf((v1 - mean) * rstd * g[lane + 64]  + b[lane + 64]);
    orow[lane + 128] = f2bf((v2 - mean) * rstd * g[lane + 128] + b[lane + 128]);
}

// ---------------- weight transpose + bf16 convert: WT[n][k] = W[k][n] ----------------
__global__ __launch_bounds__(256) void tconv_kernel(
    const float* __restrict__ W, u16* __restrict__ WT, int K, int N)
{
    int idx = blockIdx.x * 256 + threadIdx.x;
    if (idx >= N * K) return;
    int n = idx / K, k = idx % K;
    WT[idx] = f2bf(W[(size_t)k * N + n]);
}

// ---------------- bias table materialization: biasf[wt][head][i][j] (bf16) ----------------
__global__ __launch_bounds__(256) void biasmat_kernel(
    const float* __restrict__ btab, const int* __restrict__ pidx,
    u16* __restrict__ biasf)
{
    int wt = blockIdx.x, head = blockIdx.y;
    size_t obase = ((size_t)wt * 6 + head) * (LW * LW);
    for (int idx = threadIdx.x; idx < LW * LW; idx += 256) {
        int p = pidx[idx];
        biasf[obase + idx] = f2bf(btab[((size_t)p * 64 + wt) * 6 + head]);
    }
}

// ---------------- bf16 MFMA GEMM: tile 128x64, BK=64, 4 waves (2x2) ----------------
// A: [M][K] bf16 contiguous.  BT: [N][K] bf16.  C epilogue by MODE:
// MODE 0: QKV  -> qkvb bf16, (acc+bias)*QSCALE for cols<192
// MODE 1: PROJ -> x[token] += acc+bias (window-reverse + un-roll scatter)
// MODE 2: MLP1 -> hidb bf16, exact GELU
// MODE 3: MLP2 -> x[row] += acc+bias
template <int MODE>
__global__ __launch_bounds__(256) void mm_kernel(
    const u16* __restrict__ A, const u16* __restrict__ BT,
    const float* __restrict__ bias, void* __restrict__ Cvoid,
    int N, int K, int row0, int roll)
{
    __shared__ alignas(16) u16 As[128 * 72];   // [m][k], stride 72 (144B)
    __shared__ alignas(16) u16 Bs[64 * 72];    // [n][k], stride 72
    int tid = threadIdx.x;
    int mb = blockIdx.y * 128, nb = blockIdx.x * 64;
    int wave = tid >> 6, lane = tid & 63;
    int mh = wave >> 1, nh = wave & 1;         // wave tile 64(M) x 32(N)
    int lr = lane & 15, g = lane >> 4;

    f4_t acc[4][2];
    #pragma unroll
    for (int mi = 0; mi < 4; mi++)
        #pragma unroll
        for (int ni = 0; ni < 2; ni++)
            acc[mi][ni] = (f4_t){0.f, 0.f, 0.f, 0.f};

    for (int k0 = 0; k0 < K; k0 += 64) {
        // stage A: 128 rows x 64 k = 1024 x 8-u16 chunks
        #pragma unroll
        for (int it = 0; it < 4; it++) {
            int idx = it * 256 + tid;
            int r = idx >> 3, kc = idx & 7;
            *(bf8_t*)&As[r * 72 + kc * 8] =
                *(const bf8_t*)&A[(size_t)(mb + r) * K + k0 + kc * 8];
        }
        // stage B: 64 rows x 64 k = 512 chunks
        #pragma unroll
        for (int it = 0; it < 2; it++) {
            int idx = it * 256 + tid;
            int r = idx >> 3, kc = idx & 7;
            *(bf8_t*)&Bs[r * 72 + kc * 8] =
                *(const bf8_t*)&BT[(size_t)(nb + r) * K + k0 + kc * 8];
        }
        __syncthreads();
        #pragma unroll
        for (int ks = 0; ks < 2; ks++) {
            bf8_t bfr[2];
            #pragma unroll
            for (int ni = 0; ni < 2; ni++)
                bfr[ni] = *(const bf8_t*)&Bs[(nh * 32 + ni * 16 + lr) * 72 + ks * 32 + g * 8];
            #pragma unroll
            for (int mi = 0; mi < 4; mi++) {
                bf8_t afr = *(const bf8_t*)&As[(mh * 64 + mi * 16 + lr) * 72 + ks * 32 + g * 8];
                #pragma unroll
                for (int ni = 0; ni < 2; ni++)
                    acc[mi][ni] = __builtin_amdgcn_mfma_f32_16x16x32_bf16(
                        afr, bfr[ni], acc[mi][ni], 0, 0, 0);
            }
        }
        __syncthreads();
    }

    // epilogue. C layout: col = lane&15, row = (lane>>4)*4 + reg
    #pragma unroll
    for (int mi = 0; mi < 4; mi++) {
        int rbase = mb + mh * 64 + mi * 16 + g * 4;
        int tok[4];
        if (MODE == 1) {
            #pragma unroll
            for (int r = 0; r < 4; r++)
                tok[r] = win_row_to_token(row0 + rbase + r, roll);
        }
        #pragma unroll
        for (int ni = 0; ni < 2; ni++) {
            int col = nb + nh * 32 + ni * 16 + lr;
            float bb = bias[col];
            #pragma unroll
            for (int r = 0; r < 4; r++) {
                float v = acc[mi][ni][r] + bb;
                if (MODE == 0) {
                    if (col < 192) v *= QSCALE;
                    ((u16*)Cvoid)[(size_t)(rbase + r) * 576 + col] = f2bf(v);
                } else if (MODE == 1) {
                    ((float*)Cvoid)[(size_t)tok[r] * C + col] += v;
                } else if (MODE == 2) {
                    v = 0.5f * v * (1.0f + erff(v * 0.70710678118654752f));
                    ((u16*)Cvoid)[(size_t)(rbase + r) * 768 + col] = f2bf(v);
                } else {
                    ((float*)Cvoid)[(size_t)(row0 + rbase + r) * C + col] += v;
                }
            }
        }
    }
}

// ---------------- MFMA attention ----------------
__global__ __launch_bounds__(192) void attn_kernel(
    const u16* __restrict__ qkvb, const u16* __restrict__ biasf,
    u16* __restrict__ attnb, int win0, int roll)
{
    __shared__ alignas(16) u16 Qs[144 * 40];
    __shared__ alignas(16) u16 Ks[144 * 40];
    __shared__ alignas(16) u16 Vt[32 * 168];
    __shared__ alignas(16) u16 Ps[3 * 16 * 168];
    __shared__ int region[144];

    int wl = blockIdx.x, head = blockIdx.y;
    int wi = win0 + wl, wt = wi & 63;
    int tid = threadIdx.x;

    const u16* base = qkvb + (size_t)wl * LW * 576;
    for (int idx = tid; idx < 144 * 32; idx += 192) {
        int l = idx >> 5, d = idx & 31;
        const u16* row = base + (size_t)l * 576 + head * 32;
        Qs[l * 40 + d] = row[d];
        Ks[l * 40 + d] = row[192 + d];
        Vt[d * 168 + l] = row[384 + d];
    }
    for (int idx = tid; idx < 32 * 24; idx += 192) {
        int d = idx / 24, c2 = 144 + idx % 24;
        Vt[d * 168 + c2] = 0;
    }
    for (int idx = tid; idx < 48 * 24; idx += 192) {
        int rw = idx / 24, c2 = 144 + idx % 24;
        Ps[rw * 168 + c2] = 0;
    }
    if (tid < 144) {
        int nz = wi >> 8, nh = (wi >> 4) & 15, nw = wi & 15;
        int iz = tid / 72, rr = tid % 72, ih = rr / 12, iw = rr % 12;
        int z = nz * 2 + iz, h = nh * 6 + ih, w = nw * 12 + iw;
        int rz = (z < 6) ? 0 : ((z < 7) ? 1 : 2);
        int rh = (h < 90) ? 0 : ((h < 93) ? 1 : 2);
        int rw2 = (w < 180) ? 0 : ((w < 186) ? 1 : 2);
        region[tid] = rz * 9 + rh * 3 + rw2;
    }
    __syncthreads();

    int wave = tid >> 6, lane = tid & 63;
    int lr = lane & 15, g = lane >> 4;
    u16* Pbuf = &Ps[wave * 16 * 168];

    for (int itl = 0; itl < 3; itl++) {
        int it = wave * 3 + itl;
        bf8_t aQ = *(const bf8_t*)&Qs[(it * 16 + lr) * 40 + g * 8];
        f4_t s[9];
        #pragma unroll
        for (int jt = 0; jt < 9; jt++) {
            bf8_t bK = *(const bf8_t*)&Ks[(jt * 16 + lr) * 40 + g * 8];
            f4_t z4 = {0.f, 0.f, 0.f, 0.f};
            s[jt] = __builtin_amdgcn_mfma_f32_16x16x32_bf16(aQ, bK, z4, 0, 0, 0);
        }
        int rowbase = it * 16 + g * 4;
        const u16* bb = biasf + ((size_t)(wt * 6 + head) * LW + rowbase) * LW + lr;
        int regRow[4], regCol[9];
        if (roll) {
            #pragma unroll
            for (int r = 0; r < 4; r++) regRow[r] = region[rowbase + r];
            #pragma unroll
            for (int jt = 0; jt < 9; jt++) regCol[jt] = region[jt * 16 + lr];
        }
        float m4[4] = {-1e30f, -1e30f, -1e30f, -1e30f};
        #pragma unroll
        for (int jt = 0; jt < 9; jt++)
            #pragma unroll
            for (int r = 0; r < 4; r++) {
                float v = s[jt][r] + bf2f(bb[r * LW + jt * 16]);
                if (roll && (regCol[jt] != regRow[r])) v -= 100.0f;
                s[jt][r] = v;
                m4[r] = fmaxf(m4[r], v);
            }
        #pragma unroll
        for (int off = 1; off < 16; off <<= 1)
            #pragma unroll
            for (int r = 0; r < 4; r++)
                m4[r] = fmaxf(m4[r], __shfl_xor(m4[r], off, 64));
        float l4[4] = {0.f, 0.f, 0.f, 0.f};
        #pragma unroll
        for (int jt = 0; jt < 9; jt++)
            #pragma unroll
            for (int r = 0; r < 4; r++) {
                float p = __expf(s[jt][r] - m4[r]);
                s[jt][r] = p;
                l4[r] += p;
            }
        #pragma unroll
        for (int off = 1; off < 16; off <<= 1)
            #pragma unroll
            for (int r = 0; r < 4; r++)
                l4[r] += __shfl_xor(l4[r], off, 64);
        float inv4[4];
        #pragma unroll
        for (int r = 0; r < 4; r++) inv4[r] = 1.0f / l4[r];

        __syncthreads();
        #pragma unroll
        for (int jt = 0; jt < 9; jt++)
            #pragma unroll
            for (int r = 0; r < 4; r++)
                Pbuf[(g * 4 + r) * 168 + jt * 16 + lr] = f2bf(s[jt][r] * inv4[r]);
        __syncthreads();

        #pragma unroll
        for (int dt = 0; dt < 2; dt++) {
            f4_t acc = {0.f, 0.f, 0.f, 0.f};
            #pragma unroll
            for (int kt = 0; kt < 5; kt++) {
                bf8_t aP = *(const bf8_t*)&Pbuf[lr * 168 + kt * 32 + g * 8];
                bf8_t bV = *(const bf8_t*)&Vt[(dt * 16 + lr) * 168 + kt * 32 + g * 8];
                acc = __builtin_amdgcn_mfma_f32_16x16x32_bf16(aP, bV, acc, 0, 0, 0);
            }
            #pragma unroll
            for (int r = 0; r < 4; r++)
                attnb[(size_t)(wl * LW + rowbase + r) * 192 + head * 32 + dt * 16 + lr]
                    = f2bf(acc[r]);
        }
    }
}

extern "C" void kernel_launch(void* const* d_in, const int* in_sizes, int n_in,
                              void* d_out, int out_size, void* d_ws, size_t ws_size,
                              hipStream_t stream)
{
    (void)in_sizes; (void)n_in; (void)out_size; (void)ws_size;
    const float* x_in   = (const float*)d_in[0];
    const float* qkv_w  = (const float*)d_in[1];
    const float* qkv_b  = (const float*)d_in[2];
    const float* proj_w = (const float*)d_in[3];
    const float* proj_b = (const float*)d_in[4];
    const float* btab   = (const float*)d_in[5];
    const float* n1g    = (const float*)d_in[6];
    const float* n1b    = (const float*)d_in[7];
    const float* n2g    = (const float*)d_in[8];
    const float* n2b    = (const float*)d_in[9];
    const float* w1     = (const float*)d_in[10];
    const float* b1     = (const float*)d_in[11];
    const float* w2     = (const float*)d_in[12];
    const float* b2     = (const float*)d_in[13];
    const int*   pidx   = (const int*)d_in[14];

    float* x   = (float*)d_out;
    // full-size (no-chunk) workspace layout, all u16:
    //   biasf : 64*6*144*144        =  7,962,624  (15.9 MB)
    //   wT    : 2*442368            =    884,736  ( 1.8 MB)
    //   xnc   : 147456*192          = 28,311,552  (56.6 MB)
    //   qkvb  : 147456*576          = 84,934,656  (169.9 MB)
    //   attnb : 147456*192          = 28,311,552  (56.6 MB)
    //   hidb  : 147456*768          = 113,246,208 -> overlaps qkvb+attnb exactly
    // total = 300.8 MB  (< poison-fill-observed ws of ~453 MB)
    u16* biasf = (u16*)d_ws;
    u16* wT    = biasf + (size_t)64 * 6 * LW * LW;
    u16* xnc   = wT + 884736;
    u16* qkvb  = xnc + (size_t)NTOK * C;
    u16* attnb = qkvb + (size_t)NTOK * 576;
    u16* hidb  = qkvb;                                   // NTOK*768 overlaps qkvb+attnb

    // per-block transposed-weight offsets (u16)
    const size_t WBLK = 442368;   // 576*192 + 192*192 + 768*192 + 192*768
    const size_t OQKV = 0, OPROJ = 110592, OW1 = 147456, OW2 = 294912;

    hipMemcpyAsync(x, x_in, (size_t)NTOK * C * sizeof(float),
                   hipMemcpyDeviceToDevice, stream);

    // one-time weight transpose/convert (both blocks)
    for (int blk = 0; blk < 2; blk++) {
        u16* wb = wT + blk * WBLK;
        tconv_kernel<<<(576 * 192 + 255) / 256, 256, 0, stream>>>(
            qkv_w + (size_t)blk * C * 576, wb + OQKV, C, 576);
        tconv_kernel<<<(192 * 192 + 255) / 256, 256, 0, stream>>>(
            proj_w + (size_t)blk * C * C, wb + OPROJ, C, 192);
        tconv_kernel<<<(768 * 192 + 255) / 256, 256, 0, stream>>>(
            w1 + (size_t)blk * C * 768, wb + OW1, C, 768);
        tconv_kernel<<<(192 * 768 + 255) / 256, 256, 0, stream>>>(
            w2 + (size_t)blk * 768 * C, wb + OW2, 768, 192);
    }

    for (int blk = 0; blk < 2; blk++) {
        int roll = blk & 1;
        u16* wb = wT + blk * WBLK;
        biasmat_kernel<<<dim3(64, 6), 256, 0, stream>>>(
            btab + (size_t)blk * NPOS * 64 * 6, pidx, biasf);
        // ---- attention half (full size, single pass) ----
        ln_kernel<<<NTOK / 4, 256, 0, stream>>>(
            x, n1g + blk * C, n1b + blk * C, xnc, 0, 1, roll);
        mm_kernel<0><<<dim3(9, NTOK / 128), 256, 0, stream>>>(
            xnc, wb + OQKV, qkv_b + blk * 576, qkvb, 576, C, 0, roll);
        attn_kernel<<<dim3(NWIN, NHEADS), 192, 0, stream>>>(
            qkvb, biasf, attnb, 0, roll);
        mm_kernel<1><<<dim3(3, NTOK / 128), 256, 0, stream>>>(
            attnb, wb + OPROJ, proj_b + blk * C, x, 192, C, 0, roll);
        // ---- MLP half (full size, single pass) ----
        ln_kernel<<<NTOK / 4, 256, 0, stream>>>(
            x, n2g + blk * C, n2b + blk * C, xnc, 0, 0, 0);
        mm_kernel<2><<<dim3(12, NTOK / 128), 256, 0, stream>>>(
            xnc, wb + OW1, b1 + blk * 768, hidb, 768, C, 0, 0);
        mm_kernel<3><<<dim3(3, NTOK / 128), 256, 0, stream>>>(
            hidb, wb + OW2, b2 + blk * C, x, 192, 768, 0, 0);
    }
}